// Round 15
// baseline (1017.461 us; speedup 1.0000x reference)
//
#include <hip/hip_runtime.h>

#define DD 256

typedef unsigned short u16;
typedef unsigned int u32;
using bf16x8 = __attribute__((ext_vector_type(8))) short;     // 8 bf16 (4 VGPRs)
using f16x8  = __attribute__((ext_vector_type(8))) _Float16;  // 8 fp16 (4 VGPRs)
using f32x4  = __attribute__((ext_vector_type(4))) float;

#define GLB_PTR(p) ((const __attribute__((address_space(1))) u32*)(p))
#define LDS_PTR(p) ((__attribute__((address_space(3))) u32*)(p))

// ---- bfx2 helpers: uint32 = hi_bf16 (bits 15:0) | lo_bf16 (bits 31:16) ----

__device__ __forceinline__ u32 f2bfx2(float v) {
  u32 b = __float_as_uint(v);
  u32 hi = (b + 0x7fffu + ((b >> 16) & 1u)) >> 16;  // RNE bf16
  float hf = __uint_as_float(hi << 16);
  float lof = v - hf;
  u32 b2 = __float_as_uint(lof);
  u32 lo = (b2 + 0x7fffu + ((b2 >> 16) & 1u)) >> 16;
  return hi | (lo << 16);
}

// ---- fp16 helpers ----
__device__ __forceinline__ u16 f2h(float f) {
  _Float16 h = (_Float16)f;
  return __builtin_bit_cast(unsigned short, h);
}
__device__ __forceinline__ float h2f(u16 x) {
  return (float)__builtin_bit_cast(_Float16, x);
}

__device__ __forceinline__ bf16x8 as_bf16x8(uint4 u) {
  union { uint4 u; bf16x8 v; } c;
  c.u = u;
  return c.v;
}
__device__ __forceinline__ f16x8 as_f16x8(uint4 u) {
  union { uint4 u; f16x8 v; } c;
  c.u = u;
  return c.v;
}

// deinterleave 8 packed bfx2 (a,b) into hi-plane / lo-plane bf16x8
__device__ __forceinline__ void unpack8(uint4 a, uint4 b, bf16x8& hi, bf16x8& lo) {
  union { u32 w[4]; bf16x8 v; } H, L;
  H.w[0] = __builtin_amdgcn_perm(a.y, a.x, 0x05040100u);
  L.w[0] = __builtin_amdgcn_perm(a.y, a.x, 0x07060302u);
  H.w[1] = __builtin_amdgcn_perm(a.w, a.z, 0x05040100u);
  L.w[1] = __builtin_amdgcn_perm(a.w, a.z, 0x07060302u);
  H.w[2] = __builtin_amdgcn_perm(b.y, b.x, 0x05040100u);
  L.w[2] = __builtin_amdgcn_perm(b.y, b.x, 0x07060302u);
  H.w[3] = __builtin_amdgcn_perm(b.w, b.z, 0x05040100u);
  L.w[3] = __builtin_amdgcn_perm(b.w, b.z, 0x07060302u);
  hi = H.v;
  lo = L.v;
}

// packed B-plane layout: fragment-contiguous. off = ((kc32*4+w)*4+r)*512 + lane*8
__device__ __forceinline__ int packoff(int col, int k) {
  int w = col >> 6, r = (col >> 4) & 3, c16 = col & 15;
  int kc = k >> 5, q = (k >> 3) & 3, j = k & 7;
  return ((kc * 4 + w) * 4 + r) * 512 + (q * 16 + c16) * 8 + j;
}

// ---------------- CSR build ----------------

__global__ void zero_i32_kernel(int* p, int n) {
  int i = blockIdx.x * 256 + threadIdx.x;
  if (i < n) p[i] = 0;
}

__global__ void zero_f32_kernel(float* p, int n) {
  int i = blockIdx.x * 256 + threadIdx.x;
  if (i < n) p[i] = 0.f;
}

__global__ void count_kernel(const int* __restrict__ dst, int* __restrict__ cnt, int e) {
  int i = blockIdx.x * 256 + threadIdx.x;
  if (i < e) atomicAdd(&cnt[dst[i]], 1);
}

__global__ void scan_block_kernel(const int* __restrict__ cnt, int* __restrict__ out,
                                  int* __restrict__ bsum, int n) {
  __shared__ int sh[256];
  int tid = threadIdx.x;
  int base = blockIdx.x * 1024 + tid * 4;
  int v0 = (base + 0 < n) ? cnt[base + 0] : 0;
  int v1 = (base + 1 < n) ? cnt[base + 1] : 0;
  int v2 = (base + 2 < n) ? cnt[base + 2] : 0;
  int v3 = (base + 3 < n) ? cnt[base + 3] : 0;
  int s = v0 + v1 + v2 + v3;
  sh[tid] = s;
  __syncthreads();
  for (int d = 1; d < 256; d <<= 1) {
    int t = (tid >= d) ? sh[tid - d] : 0;
    __syncthreads();
    sh[tid] += t;
    __syncthreads();
  }
  int excl = sh[tid] - s;
  if (base + 0 < n) out[base + 0] = excl;
  excl += v0;
  if (base + 1 < n) out[base + 1] = excl;
  excl += v1;
  if (base + 2 < n) out[base + 2] = excl;
  excl += v2;
  if (base + 3 < n) out[base + 3] = excl;
  if (tid == 255) bsum[blockIdx.x] = sh[255];
}

__global__ void scan_partials_kernel(int* bsum, int nb) {
  if (threadIdx.x == 0 && blockIdx.x == 0) {
    int acc = 0;
    for (int i = 0; i < nb; ++i) { int t = bsum[i]; bsum[i] = acc; acc += t; }
  }
}

__global__ void finalize_kernel(int* __restrict__ off, const int* __restrict__ bsum,
                                int* __restrict__ cursor, const int* __restrict__ cnt,
                                float* __restrict__ dis, int n, int e) {
  int i = blockIdx.x * 256 + threadIdx.x;
  if (i < n) {
    int o = off[i] + bsum[i >> 10];
    off[i] = o;
    cursor[i] = o;
    dis[i] = rsqrtf((float)(cnt[i] + 1));  // deg includes self-loop
  }
  if (i == 0 && blockIdx.x == 0) off[n] = e;
}

// fill with precomputed per-edge norm = dis[src]*dis[dst]
__global__ void fill_kernel(const int* __restrict__ src, const int* __restrict__ dst,
                            int* __restrict__ cursor, const float* __restrict__ dis,
                            int2* __restrict__ csrE, int e) {
  int i = blockIdx.x * 256 + threadIdx.x;
  if (i < e) {
    int s = src[i];
    int d = dst[i];
    int p = atomicAdd(&cursor[d], 1);
    float w = dis[s] * dis[d];
    csrE[p] = make_int2(s, __float_as_int(w));
  }
}

// ---------------- degree sort (counting sort, heavy-first) ----------------

__global__ void hist_kernel(const int* __restrict__ cnt, int* __restrict__ hist, int n) {
  int i = blockIdx.x * 256 + threadIdx.x;
  if (i < n) {
    int d = cnt[i];
    if (d > 255) d = 255;
    atomicAdd(&hist[255 - d], 1);  // bin 0 = heaviest
  }
}

__global__ void hist_scan_kernel(int* __restrict__ hist, int* __restrict__ hcur) {
  __shared__ int sh[256];
  int t = threadIdx.x;
  int v = hist[t];
  sh[t] = v;
  __syncthreads();
  for (int d = 1; d < 256; d <<= 1) {
    int x = (t >= d) ? sh[t - d] : 0;
    __syncthreads();
    sh[t] += x;
    __syncthreads();
  }
  hcur[t] = sh[t] - v;  // exclusive prefix
}

__global__ void perm_kernel(const int* __restrict__ cnt, int* __restrict__ hcur,
                            int* __restrict__ perm, int n) {
  int i = blockIdx.x * 256 + threadIdx.x;
  if (i < n) {
    int d = cnt[i];
    if (d > 255) d = 255;
    int p = atomicAdd(&hcur[255 - d], 1);
    perm[p] = i;
  }
}

// ---------------- activation prep: x fp32 -> bfx2 ----------------

__global__ void xsplit_kernel(const float* __restrict__ x, u32* __restrict__ xq, int n) {
  int i = blockIdx.x * 256 + threadIdx.x;
  if (i < n) xq[i] = f2bfx2(x[i]);
}

// ---------------- weight prep (packed layout) ----------------

__global__ void wsplit_all_kernel(const float* __restrict__ fl_W, const float* __restrict__ conv1_W,
                                  const float* __restrict__ convs_W, u16* __restrict__ flHi,
                                  u16* __restrict__ flLo, u16* __restrict__ cvF) {
  int j = blockIdx.x;   // output column
  int m = blockIdx.y;   // matrix id
  int k = threadIdx.x;  // input row
  if (m == 0) {
    if (k < 128) {
      u32 p = f2bfx2(fl_W[(size_t)k * 256 + j]);
      int off = packoff(j, k);
      flHi[off] = (u16)(p & 0xffffu);
      flLo[off] = (u16)(p >> 16);
    }
  } else {
    int c = m - 1;
    const float* W = (c == 0) ? conv1_W : convs_W + (size_t)(c - 1) * 65536;
    cvF[(size_t)c * 65536 + packoff(j, k)] = f2h(W[(size_t)k * 256 + j]);
  }
}

// tr prep + BN finalize merged: thread k reduces channel-k shards to scale/shift,
// scales W row k, and the block reduces shift@W into bias_out[j]. grid 256.
__global__ void wsplit_fold_kernel(const float* __restrict__ W, const float* __restrict__ shard,
                                   const float* __restrict__ g, const float* __restrict__ b,
                                   const float* __restrict__ bt, u16* __restrict__ trF,
                                   float* __restrict__ bias_out, float inv_n) {
  __shared__ float red[256];
  int j = blockIdx.x;
  int k = threadIdx.x;
  float s = 0.f, q = 0.f;
#pragma unroll 8
  for (int i = 0; i < 64; ++i) {
    s += shard[(size_t)i * 512 + k];
    q += shard[(size_t)i * 512 + 256 + k];
  }
  float mu = s * inv_n;
  float var = q * inv_n - mu * mu;
  float inv = rsqrtf(var + 1e-5f);
  float sc = g[k] * inv;
  float sh = b[k] - mu * sc;
  float w = W[(size_t)k * 256 + j];
  trF[packoff(j, k)] = f2h(w * sc);
  red[k] = sh * w;
  __syncthreads();
  for (int d = 128; d > 0; d >>= 1) {
    if (k < d) red[k] += red[k + d];
    __syncthreads();
  }
  if (k == 0) bias_out[j] = bt[j] + red[0];
}

// ---------------- MFMA GEMM building blocks ----------------
// Block = 64 rows x 256 cols, 4 waves; wave owns 64 cols, all 64 rows (acc 4x4).

// bfx2 A-fragment (split path), row stride 32 u32, key (R&7)
__device__ __forceinline__ void afrag32(const u32* Asbase, int R, int q, bf16x8& ah, bf16x8& al) {
  int s = (R & 7) << 4;
  const u32* row = Asbase + R * 32;
  uint4 a0 = *(const uint4*)(row + ((((q * 32)) ^ s) >> 2));
  uint4 a1 = *(const uint4*)(row + ((((q * 32) + 16) ^ s) >> 2));
  unpack8(a0, a1, ah, al);
}

// fp16 A-fragment from 64-k stage: row = 64 fp16 (32 u32); slot = (ch*4+q)^(R&7)
__device__ __forceinline__ f16x8 afrag64(const u32* As, int R, int ch, int q) {
  int s = (ch * 4 + q) ^ (R & 7);
  return as_f16x8(*(const uint4*)(As + R * 32 + s * 4));
}

// fl+conv1 fused: A = xq (bfx2, K1=128, split bf16); T fp16 in LDS; C = T @ W2 (fp16 MFMA)
__global__ __launch_bounds__(256) void fused_fl_kernel(
    const u32* __restrict__ Aq, const u16* __restrict__ W1h, const u16* __restrict__ W1l,
    const float* __restrict__ bias1, const u16* __restrict__ W2f, u16* __restrict__ C,
    int nrows) {
  constexpr int NK1 = 4;  // 128/32
  __shared__ __align__(16) u32 As[2][2048];
  __shared__ __align__(16) u16 T[64 * 256];
  const int tid = threadIdx.x;
  const int lane = tid & 63;
  const int wave = tid >> 6;
  const int row0 = blockIdx.x * 64;
  const int q = lane >> 4;
  const int r16 = lane & 15;

  int sRowG[2], sOff[2];
#pragma unroll
  for (int c = 0; c < 2; ++c) {
    int row_l = c * 32 + wave * 8 + (lane >> 3);
    int grow = row0 + row_l;
    if (grow > nrows - 1) grow = nrows - 1;
    sRowG[c] = grow;
    sOff[c] = ((lane & 7) * 4) ^ ((row_l & 7) << 2);
  }

  int bBase[4];
#pragma unroll
  for (int r = 0; r < 4; ++r) bBase[r] = (wave * 4 + r) * 512 + lane * 8;

  f32x4 acc[4][4];
#pragma unroll
  for (int i = 0; i < 4; ++i)
#pragma unroll
    for (int r = 0; r < 4; ++r) acc[i][r] = (f32x4){0.f, 0.f, 0.f, 0.f};

  auto stage = [&](int buf, int kc32) {
#pragma unroll
    for (int c = 0; c < 2; ++c) {
      const u32* gsrc = Aq + (size_t)sRowG[c] * 128 + kc32 * 32 + sOff[c];
      u32* ldst = &As[buf][c * 1024 + wave * 256];
      __builtin_amdgcn_global_load_lds(GLB_PTR(gsrc), LDS_PTR(ldst), 16, 0, 0);
    }
  };

  stage(0, 0);
  __syncthreads();
  int buf = 0;
#pragma unroll
  for (int kc = 0; kc < NK1; ++kc) {
    if (kc + 1 < NK1) stage(buf ^ 1, kc + 1);
    uint4 BH[4], BL[4];
#pragma unroll
    for (int r = 0; r < 4; ++r) {
      BH[r] = *(const uint4*)(W1h + bBase[r] + kc * 8192);
      BL[r] = *(const uint4*)(W1l + bBase[r] + kc * 8192);
    }
    bf16x8 ah[4], al[4];
#pragma unroll
    for (int i = 0; i < 4; ++i) afrag32(As[buf], i * 16 + r16, q, ah[i], al[i]);
#pragma unroll
    for (int r = 0; r < 4; ++r) {
      bf16x8 bh = as_bf16x8(BH[r]);
      bf16x8 bl = as_bf16x8(BL[r]);
#pragma unroll
      for (int i = 0; i < 4; ++i) {
        acc[i][r] = __builtin_amdgcn_mfma_f32_16x16x32_bf16(ah[i], bh, acc[i][r], 0, 0, 0);
        acc[i][r] = __builtin_amdgcn_mfma_f32_16x16x32_bf16(al[i], bh, acc[i][r], 0, 0, 0);
        acc[i][r] = __builtin_amdgcn_mfma_f32_16x16x32_bf16(ah[i], bl, acc[i][r], 0, 0, 0);
      }
    }
    __syncthreads();
    buf ^= 1;
  }

  // epilogue 1 -> fp16 swizzled LDS tile T
#pragma unroll
  for (int r = 0; r < 4; ++r) {
    int col = wave * 64 + r * 16 + r16;
    float bv = bias1[col];
#pragma unroll
    for (int i = 0; i < 4; ++i) {
#pragma unroll
      for (int g = 0; g < 4; ++g) {
        int row = i * 16 + q * 4 + g;
        float v = acc[i][r][g] + bv;
        *(u16*)((char*)T + row * 512 + ((col * 2) ^ ((row & 7) << 4))) = f2h(v);
      }
    }
  }

  // phase 2: T @ W2 (fp16)
#pragma unroll
  for (int i = 0; i < 4; ++i)
#pragma unroll
    for (int r = 0; r < 4; ++r) acc[i][r] = (f32x4){0.f, 0.f, 0.f, 0.f};
  __syncthreads();

#pragma unroll
  for (int kc = 0; kc < 8; ++kc) {
    uint4 BF[4];
#pragma unroll
    for (int r = 0; r < 4; ++r) BF[r] = *(const uint4*)(W2f + bBase[r] + kc * 8192);
    f16x8 af[4];
#pragma unroll
    for (int i = 0; i < 4; ++i) {
      int row = i * 16 + r16;
      int base = kc * 64 + q * 16;
      af[i] = as_f16x8(*(const uint4*)((char*)T + row * 512 + (base ^ ((row & 7) << 4))));
    }
#pragma unroll
    for (int r = 0; r < 4; ++r) {
      f16x8 bf = as_f16x8(BF[r]);
#pragma unroll
      for (int i = 0; i < 4; ++i)
        acc[i][r] = __builtin_amdgcn_mfma_f32_16x16x32_f16(af[i], bf, acc[i][r], 0, 0, 0);
    }
  }

#pragma unroll
  for (int r = 0; r < 4; ++r) {
    int col = wave * 64 + r * 16 + r16;
#pragma unroll
    for (int i = 0; i < 4; ++i) {
#pragma unroll
      for (int g = 0; g < 4; ++g) {
        int row = row0 + i * 16 + q * 4 + g;
        if (row < nrows) C[(size_t)row * 256 + col] = f2h(acc[i][r][g]);
      }
    }
  }
}

// tr(+conv) fused, full fp16, BK=64: A = h_agg fp16; T = relu(A@W1f+bias1) in LDS;
// C = T @ W2f.
__global__ __launch_bounds__(256) void fused_h_kernel(
    const u16* __restrict__ Ah, const u16* __restrict__ W1f, const float* __restrict__ bias1,
    const u16* __restrict__ W2f, u16* __restrict__ C, int nrows) {
  __shared__ __align__(16) u32 As[2][2048];  // 2 x 8KB fp16 A stages (64 rows x 64 fp16)
  __shared__ __align__(16) u16 T[64 * 256];  // 32KB fp16 intermediate
  const int tid = threadIdx.x;
  const int lane = tid & 63;
  const int wave = tid >> 6;
  const int row0 = blockIdx.x * 64;
  const int q = lane >> 4;
  const int r16 = lane & 15;

  int sRowG[2], sOffH[2];
#pragma unroll
  for (int c = 0; c < 2; ++c) {
    int row_l = c * 32 + wave * 8 + (lane >> 3);
    int grow = row0 + row_l;
    if (grow > nrows - 1) grow = nrows - 1;
    sRowG[c] = grow;
    sOffH[c] = ((lane & 7) ^ (row_l & 7)) * 8;  // fp16 units within 64-wide row
  }

  int bBase[4];
#pragma unroll
  for (int r = 0; r < 4; ++r) bBase[r] = (wave * 4 + r) * 512 + lane * 8;

  f32x4 acc[4][4];
#pragma unroll
  for (int i = 0; i < 4; ++i)
#pragma unroll
    for (int r = 0; r < 4; ++r) acc[i][r] = (f32x4){0.f, 0.f, 0.f, 0.f};

  auto stage = [&](int buf, int kc64) {
#pragma unroll
    for (int c = 0; c < 2; ++c) {
      const u16* gsrc = Ah + (size_t)sRowG[c] * 256 + kc64 * 64 + sOffH[c];
      u32* ldst = &As[buf][c * 1024 + wave * 256];
      __builtin_amdgcn_global_load_lds(GLB_PTR(gsrc), LDS_PTR(ldst), 16, 0, 0);
    }
  };

  // ---------- phase 1: A @ W1f (fp16), 4 barriers ----------
  stage(0, 0);
  __syncthreads();
  int buf = 0;
#pragma unroll
  for (int kc = 0; kc < 4; ++kc) {
    if (kc + 1 < 4) stage(buf ^ 1, kc + 1);
#pragma unroll
    for (int ch = 0; ch < 2; ++ch) {
      int kc32 = kc * 2 + ch;
      uint4 BF[4];
#pragma unroll
      for (int r = 0; r < 4; ++r) BF[r] = *(const uint4*)(W1f + bBase[r] + kc32 * 8192);
      f16x8 af[4];
#pragma unroll
      for (int i = 0; i < 4; ++i) af[i] = afrag64(As[buf], i * 16 + r16, ch, q);
#pragma unroll
      for (int r = 0; r < 4; ++r) {
        f16x8 bf = as_f16x8(BF[r]);
#pragma unroll
        for (int i = 0; i < 4; ++i)
          acc[i][r] = __builtin_amdgcn_mfma_f32_16x16x32_f16(af[i], bf, acc[i][r], 0, 0, 0);
      }
    }
    __syncthreads();
    buf ^= 1;
  }

  // epilogue 1 -> fp16 swizzled LDS tile T (relu)
#pragma unroll
  for (int r = 0; r < 4; ++r) {
    int col = wave * 64 + r * 16 + r16;
    float bv = bias1[col];
#pragma unroll
    for (int i = 0; i < 4; ++i) {
#pragma unroll
      for (int g = 0; g < 4; ++g) {
        int row = i * 16 + q * 4 + g;
        float v = fmaxf(acc[i][r][g] + bv, 0.f);
        *(u16*)((char*)T + row * 512 + ((col * 2) ^ ((row & 7) << 4))) = f2h(v);
      }
    }
  }

  // ---------- phase 2: T @ W2f (fp16, barrier-free) ----------
#pragma unroll
  for (int i = 0; i < 4; ++i)
#pragma unroll
    for (int r = 0; r < 4; ++r) acc[i][r] = (f32x4){0.f, 0.f, 0.f, 0.f};
  __syncthreads();

#pragma unroll
  for (int kc = 0; kc < 8; ++kc) {
    uint4 BF[4];
#pragma unroll
    for (int r = 0; r < 4; ++r) BF[r] = *(const uint4*)(W2f + bBase[r] + kc * 8192);
    f16x8 af[4];
#pragma unroll
    for (int i = 0; i < 4; ++i) {
      int row = i * 16 + r16;
      int base = kc * 64 + q * 16;
      af[i] = as_f16x8(*(const uint4*)((char*)T + row * 512 + (base ^ ((row & 7) << 4))));
    }
#pragma unroll
    for (int r = 0; r < 4; ++r) {
      f16x8 bf = as_f16x8(BF[r]);
#pragma unroll
      for (int i = 0; i < 4; ++i)
        acc[i][r] = __builtin_amdgcn_mfma_f32_16x16x32_f16(af[i], bf, acc[i][r], 0, 0, 0);
    }
  }

#pragma unroll
  for (int r = 0; r < 4; ++r) {
    int col = wave * 64 + r * 16 + r16;
#pragma unroll
    for (int i = 0; i < 4; ++i) {
#pragma unroll
      for (int g = 0; g < 4; ++g) {
        int row = row0 + i * 16 + q * 4 + g;
        if (row < nrows) C[(size_t)row * 256 + col] = f2h(acc[i][r][g]);
      }
    }
  }
}

// final tr standalone, fp16, BK=64: C = relu(A @ W1f + bias)
__global__ __launch_bounds__(256) void gemm_h_kernel(
    const u16* __restrict__ Ah, const u16* __restrict__ W1f, const float* __restrict__ bias,
    u16* __restrict__ C, int nrows) {
  __shared__ __align__(16) u32 As[2][2048];
  const int tid = threadIdx.x;
  const int lane = tid & 63;
  const int wave = tid >> 6;
  const int row0 = blockIdx.x * 64;
  const int q = lane >> 4;
  const int r16 = lane & 15;

  int sRowG[2], sOffH[2];
#pragma unroll
  for (int c = 0; c < 2; ++c) {
    int row_l = c * 32 + wave * 8 + (lane >> 3);
    int grow = row0 + row_l;
    if (grow > nrows - 1) grow = nrows - 1;
    sRowG[c] = grow;
    sOffH[c] = ((lane & 7) ^ (row_l & 7)) * 8;
  }

  int bBase[4];
#pragma unroll
  for (int r = 0; r < 4; ++r) bBase[r] = (wave * 4 + r) * 512 + lane * 8;

  f32x4 acc[4][4];
#pragma unroll
  for (int i = 0; i < 4; ++i)
#pragma unroll
    for (int r = 0; r < 4; ++r) acc[i][r] = (f32x4){0.f, 0.f, 0.f, 0.f};

  auto stage = [&](int buf, int kc64) {
#pragma unroll
    for (int c = 0; c < 2; ++c) {
      const u16* gsrc = Ah + (size_t)sRowG[c] * 256 + kc64 * 64 + sOffH[c];
      u32* ldst = &As[buf][c * 1024 + wave * 256];
      __builtin_amdgcn_global_load_lds(GLB_PTR(gsrc), LDS_PTR(ldst), 16, 0, 0);
    }
  };

  stage(0, 0);
  __syncthreads();
  int buf = 0;
#pragma unroll
  for (int kc = 0; kc < 4; ++kc) {
    if (kc + 1 < 4) stage(buf ^ 1, kc + 1);
#pragma unroll
    for (int ch = 0; ch < 2; ++ch) {
      int kc32 = kc * 2 + ch;
      uint4 BF[4];
#pragma unroll
      for (int r = 0; r < 4; ++r) BF[r] = *(const uint4*)(W1f + bBase[r] + kc32 * 8192);
      f16x8 af[4];
#pragma unroll
      for (int i = 0; i < 4; ++i) af[i] = afrag64(As[buf], i * 16 + r16, ch, q);
#pragma unroll
      for (int r = 0; r < 4; ++r) {
        f16x8 bf = as_f16x8(BF[r]);
#pragma unroll
        for (int i = 0; i < 4; ++i)
          acc[i][r] = __builtin_amdgcn_mfma_f32_16x16x32_f16(af[i], bf, acc[i][r], 0, 0, 0);
      }
    }
    __syncthreads();
    buf ^= 1;
  }

#pragma unroll
  for (int r = 0; r < 4; ++r) {
    int col = wave * 64 + r * 16 + r16;
    float bv = bias[col];
#pragma unroll
    for (int i = 0; i < 4; ++i) {
#pragma unroll
      for (int g = 0; g < 4; ++g) {
        int row = row0 + i * 16 + q * 4 + g;
        if (row < nrows) C[(size_t)row * 256 + col] = f2h(fmaxf(acc[i][r][g] + bv, 0.f));
      }
    }
  }
}

// ---------------- GCN gather + fused BN stats, degree-sorted, 8-edge unroll --
// m fp16 in, h_agg fp16 out; per-edge (src,norm) precomputed. BN stats fp32.

__global__ __launch_bounds__(256) void gather_kernel(
    const u16* __restrict__ m, const int* __restrict__ off,
    const int2* __restrict__ csrE, const float* __restrict__ dis,
    const float* __restrict__ bias, const int* __restrict__ perm,
    u16* __restrict__ out, float* __restrict__ shard, int n) {
  __shared__ float2 red[4][256];
  int wv = threadIdx.x >> 6;
  int lane = threadIdx.x & 63;
  int vid = blockIdx.x * 4 + wv;
  float ax = 0.f, ay = 0.f, az = 0.f, aw = 0.f;
  if (vid < n) {
    int node = perm[vid];
    float di = dis[node];
    uint2 v = *(const uint2*)(m + (size_t)node * DD + lane * 4);
    float w = di * di;
    ax = w * h2f((u16)(v.x & 0xffff)); ay = w * h2f((u16)(v.x >> 16));
    az = w * h2f((u16)(v.y & 0xffff)); aw = w * h2f((u16)(v.y >> 16));
    int e = off[node], e1 = off[node + 1];
    for (; e + 7 < e1; e += 8) {
      int2 p[8];
#pragma unroll
      for (int j = 0; j < 8; ++j) p[j] = csrE[e + j];
      uint2 u[8];
#pragma unroll
      for (int j = 0; j < 8; ++j) u[j] = *(const uint2*)(m + (size_t)p[j].x * DD + lane * 4);
#pragma unroll
      for (int j = 0; j < 8; ++j) {
        float ww = __int_as_float(p[j].y);
        ax = fmaf(ww, h2f((u16)(u[j].x & 0xffff)), ax);
        ay = fmaf(ww, h2f((u16)(u[j].x >> 16)), ay);
        az = fmaf(ww, h2f((u16)(u[j].y & 0xffff)), az);
        aw = fmaf(ww, h2f((u16)(u[j].y >> 16)), aw);
      }
    }
    for (; e + 3 < e1; e += 4) {
      int2 p[4];
#pragma unroll
      for (int j = 0; j < 4; ++j) p[j] = csrE[e + j];
      uint2 u[4];
#pragma unroll
      for (int j = 0; j < 4; ++j) u[j] = *(const uint2*)(m + (size_t)p[j].x * DD + lane * 4);
#pragma unroll
      for (int j = 0; j < 4; ++j) {
        float ww = __int_as_float(p[j].y);
        ax = fmaf(ww, h2f((u16)(u[j].x & 0xffff)), ax);
        ay = fmaf(ww, h2f((u16)(u[j].x >> 16)), ay);
        az = fmaf(ww, h2f((u16)(u[j].y & 0xffff)), az);
        aw = fmaf(ww, h2f((u16)(u[j].y >> 16)), aw);
      }
    }
    for (; e < e1; ++e) {
      int2 p0 = csrE[e];
      float w0 = __int_as_float(p0.y);
      uint2 u0 = *(const uint2*)(m + (size_t)p0.x * DD + lane * 4);
      ax = fmaf(w0, h2f((u16)(u0.x & 0xffff)), ax); ay = fmaf(w0, h2f((u16)(u0.x >> 16)), ay);
      az = fmaf(w0, h2f((u16)(u0.y & 0xffff)), az); aw = fmaf(w0, h2f((u16)(u0.y >> 16)), aw);
    }
    float4 bb = *(const float4*)(bias + lane * 4);
    ax = fmaxf(ax + bb.x, 0.f);
    ay = fmaxf(ay + bb.y, 0.f);
    az = fmaxf(az + bb.z, 0.f);
    aw = fmaxf(aw + bb.w, 0.f);
    uint2 oo;
    oo.x = (u32)f2h(ax) | ((u32)f2h(ay) << 16);
    oo.y = (u32)f2h(az) | ((u32)f2h(aw) << 16);
    *(uint2*)(out + (size_t)node * DD + lane * 4) = oo;
  }
  red[wv][lane * 4 + 0] = make_float2(ax, ax * ax);
  red[wv][lane * 4 + 1] = make_float2(ay, ay * ay);
  red[wv][lane * 4 + 2] = make_float2(az, az * az);
  red[wv][lane * 4 + 3] = make_float2(aw, aw * aw);
  __syncthreads();
  int c = threadIdx.x;
  float2 a = red[0][c], b2 = red[1][c], c2 = red[2][c], d2 = red[3][c];
  float s = (a.x + b2.x) + (c2.x + d2.x);
  float qq = (a.y + b2.y) + (c2.y + d2.y);
  float* sh = shard + (size_t)(blockIdx.x & 63) * 512;
  atomicAdd(&sh[c], s);
  atomicAdd(&sh[256 + c], qq);
}

// ---------------- global mean pool (fp16 h) ----------------

__global__ void pool_kernel(const u16* __restrict__ h, const int* __restrict__ batch,
                            float* __restrict__ pooled, int n) {
  int g = blockIdx.x;
  int c = threadIdx.x;
  int lo = 0, hi = n;
  while (lo < hi) { int mid = (lo + hi) >> 1; if (batch[mid] < g) lo = mid + 1; else hi = mid; }
  int start = lo;
  hi = n;
  while (lo < hi) { int mid = (lo + hi) >> 1; if (batch[mid] <= g) lo = mid + 1; else hi = mid; }
  int end = lo;
  float a0 = 0.f, a1 = 0.f, a2 = 0.f, a3 = 0.f;
  int r = start;
  for (; r + 3 < end; r += 4) {
    a0 += h2f(h[(size_t)(r + 0) * DD + c]);
    a1 += h2f(h[(size_t)(r + 1) * DD + c]);
    a2 += h2f(h[(size_t)(r + 2) * DD + c]);
    a3 += h2f(h[(size_t)(r + 3) * DD + c]);
  }
  for (; r < end; ++r) a0 += h2f(h[(size_t)r * DD + c]);
  float s = (a0 + a1) + (a2 + a3);
  int cg = end - start;
  pooled[g * DD + c] = s / (float)(cg > 1 ? cg : 1);
}

// ---------------- MLP head ----------------

__global__ void mlp1_kernel(const float* __restrict__ pooled, const float* __restrict__ W,
                            const float* __restrict__ b, float* __restrict__ out) {
  __shared__ float p[256];
  int g = blockIdx.x;
  int j = blockIdx.y * 256 + threadIdx.x;
  p[threadIdx.x] = pooled[g * 256 + threadIdx.x];
  __syncthreads();
  float acc = b[j];
#pragma unroll 8
  for (int k = 0; k < 512; ++k) acc = fmaf(p[k & 255], W[k * 512 + j], acc);
  out[g * 512 + j] = fmaxf(acc, 0.f);
}

__global__ void mlp2_kernel(const float* __restrict__ z1, const float* __restrict__ W,
                            const float* __restrict__ b, float* __restrict__ out) {
  __shared__ float p[512];
  int g = blockIdx.x;
  p[threadIdx.x] = z1[g * 512 + threadIdx.x];
  p[256 + threadIdx.x] = z1[g * 512 + 256 + threadIdx.x];
  __syncthreads();
  float acc = b[threadIdx.x];
#pragma unroll 8
  for (int k = 0; k < 512; ++k) acc = fmaf(p[k], W[k * 256 + threadIdx.x], acc);
  out[g * 256 + threadIdx.x] = fmaxf(acc, 0.f);
}

__global__ void mlp3_kernel(const float* __restrict__ z2, const float* __restrict__ W,
                            const float* __restrict__ b, float* __restrict__ out) {
  int g = blockIdx.x;
  int lane = threadIdx.x;
  float acc[10];
#pragma unroll
  for (int o = 0; o < 10; ++o) acc[o] = 0.f;
  for (int k = lane; k < 256; k += 64) {
    float v = z2[g * 256 + k];
#pragma unroll
    for (int o = 0; o < 10; ++o) acc[o] = fmaf(v, W[k * 10 + o], acc[o]);
  }
#pragma unroll
  for (int o = 0; o < 10; ++o) {
    float s = acc[o];
    for (int d = 32; d > 0; d >>= 1) s += __shfl_down(s, d);
    if (lane == 0) out[g * 10 + o] = s + b[o];
  }
}

// ---------------- launch ----------------

extern "C" void kernel_launch(void* const* d_in, const int* in_sizes, int n_in,
                              void* d_out, int out_size, void* d_ws, size_t ws_size,
                              hipStream_t stream) {
  const float* x = (const float*)d_in[0];
  const int* ei = (const int*)d_in[1];
  const int* batch = (const int*)d_in[2];
  const float* fl_W = (const float*)d_in[3];
  const float* fl_b = (const float*)d_in[4];
  const float* conv1_W = (const float*)d_in[5];
  const float* conv1_b = (const float*)d_in[6];
  const float* tr1_W = (const float*)d_in[7];
  const float* tr1_b = (const float*)d_in[8];
  const float* bn1_g = (const float*)d_in[9];
  const float* bn1_b = (const float*)d_in[10];
  const float* convs_W = (const float*)d_in[11];
  const float* convs_b = (const float*)d_in[12];
  const float* trs_W = (const float*)d_in[13];
  const float* trs_b = (const float*)d_in[14];
  const float* bns_g = (const float*)d_in[15];
  const float* bns_b = (const float*)d_in[16];
  const float* l1_W = (const float*)d_in[17];
  const float* l1_b = (const float*)d_in[18];
  const float* l2_W = (const float*)d_in[19];
  const float* l2_b = (const float*)d_in[20];
  const float* l3_W = (const float*)d_in[21];
  const float* l3_b = (const float*)d_in[22];

  const int N = in_sizes[0] / 128;
  const int E = in_sizes[1] / 2;
  const int G = out_size / 10;
  const int NL = in_sizes[11] / (256 * 256);
  const int* src = ei;
  const int* dst = ei + E;

  char* ws = (char*)d_ws;
  size_t o = 0;
  auto alloc = [&](size_t bytes) -> char* {
    o = (o + 255) & ~(size_t)255;
    char* p = ws + o;
    o += bytes;
    return p;
  };
  u16* hA = (u16*)alloc((size_t)N * DD * 2);   // gather out (fp16)
  u16* mF = (u16*)alloc((size_t)N * DD * 2);   // conv out / final h (fp16)
  u32* xq = (u32*)alloc((size_t)N * 128 * 4);  // x bfx2
  float* dis = (float*)alloc((size_t)N * 4);
  int* cnt = (int*)alloc((size_t)N * 4);
  int* off = (int*)alloc((size_t)(N + 1) * 4);
  int* cursor = (int*)alloc((size_t)N * 4);
  int* bsum = (int*)alloc(64 * 4);
  int* hist = (int*)alloc(256 * 4);
  int* hcur = (int*)alloc(256 * 4);
  int* perm = (int*)alloc((size_t)N * 4);
  int2* csrE = (int2*)alloc((size_t)E * 8);
  float* shards = (float*)alloc((size_t)(1 + NL) * 64 * 512 * 4);
  float* pooled = (float*)alloc((size_t)G * 256 * 4);
  float* z1 = (float*)alloc((size_t)G * 512 * 4);
  float* z2 = (float*)alloc((size_t)G * 256 * 4);
  u16* flHi = (u16*)alloc(128 * 256 * 2);
  u16* flLo = (u16*)alloc(128 * 256 * 2);
  u16* cvF = (u16*)alloc((size_t)(1 + NL) * 256 * 256 * 2);
  u16* trF = (u16*)alloc(256 * 256 * 2);
  float* trBias = (float*)alloc(256 * 4);

  dim3 b256(256);
  const int nblk = (N + 63) / 64;

  // CSR build
  zero_i32_kernel<<<(N + 255) / 256, b256, 0, stream>>>(cnt, N);
  count_kernel<<<(E + 255) / 256, b256, 0, stream>>>(dst, cnt, E);
  int nb = (N + 1023) / 1024;
  scan_block_kernel<<<nb, b256, 0, stream>>>(cnt, off, bsum, N);
  scan_partials_kernel<<<1, 64, 0, stream>>>(bsum, nb);
  finalize_kernel<<<(N + 255) / 256, b256, 0, stream>>>(off, bsum, cursor, cnt, dis, N, E);
  fill_kernel<<<(E + 255) / 256, b256, 0, stream>>>(src, dst, cursor, dis, csrE, E);

  // degree sort (heavy-first)
  zero_i32_kernel<<<1, b256, 0, stream>>>(hist, 256);
  hist_kernel<<<(N + 255) / 256, b256, 0, stream>>>(cnt, hist, N);
  hist_scan_kernel<<<1, b256, 0, stream>>>(hist, hcur);
  perm_kernel<<<(N + 255) / 256, b256, 0, stream>>>(cnt, hcur, perm, N);

  // prep
  xsplit_kernel<<<(N * 128 + 255) / 256, b256, 0, stream>>>(x, xq, N * 128);
  dim3 wgrid(256, 2 + NL);
  wsplit_all_kernel<<<wgrid, b256, 0, stream>>>(fl_W, conv1_W, convs_W, flHi, flLo, cvF);
  int shard_elems = (1 + NL) * 64 * 512;
  zero_f32_kernel<<<(shard_elems + 255) / 256, b256, 0, stream>>>(shards, shard_elems);

  // fused fl + conv1 -> m1 (fp16)
  fused_fl_kernel<<<nblk, b256, 0, stream>>>(xq, flHi, flLo, fl_b, cvF, mF, N);

  for (int L = 0; L < 1 + NL; ++L) {
    const float* bc = (L == 0) ? conv1_b : convs_b + (size_t)(L - 1) * 256;
    const float* gg = (L == 0) ? bn1_g : bns_g + (size_t)(L - 1) * 256;
    const float* gb = (L == 0) ? bn1_b : bns_b + (size_t)(L - 1) * 256;
    const float* Wt = (L == 0) ? tr1_W : trs_W + (size_t)(L - 1) * 256 * 256;
    const float* bt = (L == 0) ? tr1_b : trs_b + (size_t)(L - 1) * 256;
    float* slot = shards + (size_t)L * 64 * 512;

    gather_kernel<<<(N + 3) / 4, b256, 0, stream>>>(mF, off, csrE, dis, bc, perm, hA, slot, N);
    wsplit_fold_kernel<<<256, b256, 0, stream>>>(Wt, slot, gg, gb, bt, trF, trBias,
                                                 1.0f / (float)N);
    if (L < NL) {
      fused_h_kernel<<<nblk, b256, 0, stream>>>(hA, trF, trBias,
                                                cvF + (size_t)(L + 1) * 65536, mF, N);
    } else {
      gemm_h_kernel<<<nblk, b256, 0, stream>>>(hA, trF, trBias, mF, N);
    }
  }

  pool_kernel<<<G, b256, 0, stream>>>(mF, batch, pooled, N);
  dim3 m1grid(G, 2);
  mlp1_kernel<<<m1grid, b256, 0, stream>>>(pooled, l1_W, l1_b, z1);
  mlp2_kernel<<<G, b256, 0, stream>>>(z1, l2_W, l2_b, z2);
  mlp3_kernel<<<G, 64, 0, stream>>>(z2, l3_W, l3_b, (float*)d_out);
}

// Round 16
// 717.199 us; speedup vs baseline: 1.4187x; 1.4187x over previous
//
#include <hip/hip_runtime.h>

#define DD 256

typedef unsigned short u16;
typedef unsigned int u32;
using bf16x8 = __attribute__((ext_vector_type(8))) short;     // 8 bf16 (4 VGPRs)
using f16x8  = __attribute__((ext_vector_type(8))) _Float16;  // 8 fp16 (4 VGPRs)
using f32x4  = __attribute__((ext_vector_type(4))) float;

#define GLB_PTR(p) ((const __attribute__((address_space(1))) u32*)(p))
#define LDS_PTR(p) ((__attribute__((address_space(3))) u32*)(p))

// ---- bfx2 helpers: uint32 = hi_bf16 (bits 15:0) | lo_bf16 (bits 31:16) ----

__device__ __forceinline__ u32 f2bfx2(float v) {
  u32 b = __float_as_uint(v);
  u32 hi = (b + 0x7fffu + ((b >> 16) & 1u)) >> 16;  // RNE bf16
  float hf = __uint_as_float(hi << 16);
  float lof = v - hf;
  u32 b2 = __float_as_uint(lof);
  u32 lo = (b2 + 0x7fffu + ((b2 >> 16) & 1u)) >> 16;
  return hi | (lo << 16);
}

// ---- fp16 helpers ----
__device__ __forceinline__ u16 f2h(float f) {
  _Float16 h = (_Float16)f;
  return __builtin_bit_cast(unsigned short, h);
}
__device__ __forceinline__ float h2f(u16 x) {
  return (float)__builtin_bit_cast(_Float16, x);
}

__device__ __forceinline__ bf16x8 as_bf16x8(uint4 u) {
  union { uint4 u; bf16x8 v; } c;
  c.u = u;
  return c.v;
}
__device__ __forceinline__ f16x8 as_f16x8(uint4 u) {
  union { uint4 u; f16x8 v; } c;
  c.u = u;
  return c.v;
}

// deinterleave 8 packed bfx2 (a,b) into hi-plane / lo-plane bf16x8
__device__ __forceinline__ void unpack8(uint4 a, uint4 b, bf16x8& hi, bf16x8& lo) {
  union { u32 w[4]; bf16x8 v; } H, L;
  H.w[0] = __builtin_amdgcn_perm(a.y, a.x, 0x05040100u);
  L.w[0] = __builtin_amdgcn_perm(a.y, a.x, 0x07060302u);
  H.w[1] = __builtin_amdgcn_perm(a.w, a.z, 0x05040100u);
  L.w[1] = __builtin_amdgcn_perm(a.w, a.z, 0x07060302u);
  H.w[2] = __builtin_amdgcn_perm(b.y, b.x, 0x05040100u);
  L.w[2] = __builtin_amdgcn_perm(b.y, b.x, 0x07060302u);
  H.w[3] = __builtin_amdgcn_perm(b.w, b.z, 0x05040100u);
  L.w[3] = __builtin_amdgcn_perm(b.w, b.z, 0x07060302u);
  hi = H.v;
  lo = L.v;
}

// packed B-plane layout: fragment-contiguous. off = ((kc32*4+w)*4+r)*512 + lane*8
__device__ __forceinline__ int packoff(int col, int k) {
  int w = col >> 6, r = (col >> 4) & 3, c16 = col & 15;
  int kc = k >> 5, q = (k >> 3) & 3, j = k & 7;
  return ((kc * 4 + w) * 4 + r) * 512 + (q * 16 + c16) * 8 + j;
}

// ---------------- CSR build ----------------

__global__ void zero_i32_kernel(int* p, int n) {
  int i = blockIdx.x * 256 + threadIdx.x;
  if (i < n) p[i] = 0;
}

__global__ void zero_f32_kernel(float* p, int n) {
  int i = blockIdx.x * 256 + threadIdx.x;
  if (i < n) p[i] = 0.f;
}

__global__ void count_kernel(const int* __restrict__ dst, int* __restrict__ cnt, int e) {
  int i = blockIdx.x * 256 + threadIdx.x;
  if (i < e) atomicAdd(&cnt[dst[i]], 1);
}

__global__ void scan_block_kernel(const int* __restrict__ cnt, int* __restrict__ out,
                                  int* __restrict__ bsum, int n) {
  __shared__ int sh[256];
  int tid = threadIdx.x;
  int base = blockIdx.x * 1024 + tid * 4;
  int v0 = (base + 0 < n) ? cnt[base + 0] : 0;
  int v1 = (base + 1 < n) ? cnt[base + 1] : 0;
  int v2 = (base + 2 < n) ? cnt[base + 2] : 0;
  int v3 = (base + 3 < n) ? cnt[base + 3] : 0;
  int s = v0 + v1 + v2 + v3;
  sh[tid] = s;
  __syncthreads();
  for (int d = 1; d < 256; d <<= 1) {
    int t = (tid >= d) ? sh[tid - d] : 0;
    __syncthreads();
    sh[tid] += t;
    __syncthreads();
  }
  int excl = sh[tid] - s;
  if (base + 0 < n) out[base + 0] = excl;
  excl += v0;
  if (base + 1 < n) out[base + 1] = excl;
  excl += v1;
  if (base + 2 < n) out[base + 2] = excl;
  excl += v2;
  if (base + 3 < n) out[base + 3] = excl;
  if (tid == 255) bsum[blockIdx.x] = sh[255];
}

__global__ void scan_partials_kernel(int* bsum, int nb) {
  if (threadIdx.x == 0 && blockIdx.x == 0) {
    int acc = 0;
    for (int i = 0; i < nb; ++i) { int t = bsum[i]; bsum[i] = acc; acc += t; }
  }
}

__global__ void finalize_kernel(int* __restrict__ off, const int* __restrict__ bsum,
                                int* __restrict__ cursor, const int* __restrict__ cnt,
                                float* __restrict__ dis, int n, int e) {
  int i = blockIdx.x * 256 + threadIdx.x;
  if (i < n) {
    int o = off[i] + bsum[i >> 10];
    off[i] = o;
    cursor[i] = o;
    dis[i] = rsqrtf((float)(cnt[i] + 1));  // deg includes self-loop
  }
  if (i == 0 && blockIdx.x == 0) off[n] = e;
}

// fill with precomputed per-edge norm = dis[src]*dis[dst]
__global__ void fill_kernel(const int* __restrict__ src, const int* __restrict__ dst,
                            int* __restrict__ cursor, const float* __restrict__ dis,
                            int2* __restrict__ csrE, int e) {
  int i = blockIdx.x * 256 + threadIdx.x;
  if (i < e) {
    int s = src[i];
    int d = dst[i];
    int p = atomicAdd(&cursor[d], 1);
    float w = dis[s] * dis[d];
    csrE[p] = make_int2(s, __float_as_int(w));
  }
}

// ---------------- activation prep: x fp32 -> bfx2 ----------------

__global__ void xsplit_kernel(const float* __restrict__ x, u32* __restrict__ xq, int n) {
  int i = blockIdx.x * 256 + threadIdx.x;
  if (i < n) xq[i] = f2bfx2(x[i]);
}

// ---------------- weight prep (packed layout) ----------------

__global__ void wsplit_all_kernel(const float* __restrict__ fl_W, const float* __restrict__ conv1_W,
                                  const float* __restrict__ convs_W, u16* __restrict__ flHi,
                                  u16* __restrict__ flLo, u16* __restrict__ cvF) {
  int j = blockIdx.x;   // output column
  int m = blockIdx.y;   // matrix id
  int k = threadIdx.x;  // input row
  if (m == 0) {
    if (k < 128) {
      u32 p = f2bfx2(fl_W[(size_t)k * 256 + j]);
      int off = packoff(j, k);
      flHi[off] = (u16)(p & 0xffffu);
      flLo[off] = (u16)(p >> 16);
    }
  } else {
    int c = m - 1;
    const float* W = (c == 0) ? conv1_W : convs_W + (size_t)(c - 1) * 65536;
    cvF[(size_t)c * 65536 + packoff(j, k)] = f2h(W[(size_t)k * 256 + j]);
  }
}

// ---------------- BatchNorm finalize (reduce 64 shards) ----------------

__global__ void bn_finalize_kernel(const float* __restrict__ shard, const float* __restrict__ g,
                                   const float* __restrict__ b, float* __restrict__ scale,
                                   float* __restrict__ shift, float inv_n) {
  int c = threadIdx.x;
  float s = 0.f, q = 0.f;
#pragma unroll 8
  for (int i = 0; i < 64; ++i) {
    s += shard[(size_t)i * 512 + c];
    q += shard[(size_t)i * 512 + 256 + c];
  }
  float mu = s * inv_n;
  float var = q * inv_n - mu * mu;
  float inv = rsqrtf(var + 1e-5f);
  float sc = g[c] * inv;
  scale[c] = sc;
  shift[c] = b[c] - mu * sc;
}

// tr prep: W' = diag(scale)@Wt as fp16 packed plane; bias_out = bt + shift@Wt. grid 256.
__global__ void wsplit_fold_kernel(const float* __restrict__ W, const float* __restrict__ scale,
                                   const float* __restrict__ shift, const float* __restrict__ bt,
                                   u16* __restrict__ trF, float* __restrict__ bias_out) {
  __shared__ float red[256];
  int j = blockIdx.x;
  int k = threadIdx.x;
  float w = W[(size_t)k * 256 + j];
  trF[packoff(j, k)] = f2h(w * scale[k]);
  red[k] = shift[k] * w;
  __syncthreads();
  for (int d = 128; d > 0; d >>= 1) {
    if (k < d) red[k] += red[k + d];
    __syncthreads();
  }
  if (k == 0) bias_out[j] = bt[j] + red[0];
}

// ---------------- MFMA GEMM building blocks ----------------
// Block = 64 rows x 256 cols, 4 waves; wave owns 64 cols, all 64 rows (acc 4x4).

// bfx2 A-fragment (split path), row stride 32 u32, key (R&7)
__device__ __forceinline__ void afrag32(const u32* Asbase, int R, int q, bf16x8& ah, bf16x8& al) {
  int s = (R & 7) << 4;
  const u32* row = Asbase + R * 32;
  uint4 a0 = *(const uint4*)(row + ((((q * 32)) ^ s) >> 2));
  uint4 a1 = *(const uint4*)(row + ((((q * 32) + 16) ^ s) >> 2));
  unpack8(a0, a1, ah, al);
}

// fp16 A-fragment from 64-k stage: row = 64 fp16 (32 u32); slot = (ch*4+q)^(R&7)
__device__ __forceinline__ f16x8 afrag64(const u32* As, int R, int ch, int q) {
  int s = (ch * 4 + q) ^ (R & 7);
  return as_f16x8(*(const uint4*)(As + R * 32 + s * 4));
}

// fl+conv1 fused: A = xq (bfx2, K1=128, split bf16); T fp16 in LDS; C = T @ W2 (fp16 MFMA)
__global__ __launch_bounds__(256) void fused_fl_kernel(
    const u32* __restrict__ Aq, const u16* __restrict__ W1h, const u16* __restrict__ W1l,
    const float* __restrict__ bias1, const u16* __restrict__ W2f, u16* __restrict__ C,
    int nrows) {
  constexpr int NK1 = 4;  // 128/32
  __shared__ __align__(16) u32 As[2][2048];
  __shared__ __align__(16) u16 T[64 * 256];
  const int tid = threadIdx.x;
  const int lane = tid & 63;
  const int wave = tid >> 6;
  const int row0 = blockIdx.x * 64;
  const int q = lane >> 4;
  const int r16 = lane & 15;

  int sRowG[2], sOff[2];
#pragma unroll
  for (int c = 0; c < 2; ++c) {
    int row_l = c * 32 + wave * 8 + (lane >> 3);
    int grow = row0 + row_l;
    if (grow > nrows - 1) grow = nrows - 1;
    sRowG[c] = grow;
    sOff[c] = ((lane & 7) * 4) ^ ((row_l & 7) << 2);
  }

  int bBase[4];
#pragma unroll
  for (int r = 0; r < 4; ++r) bBase[r] = (wave * 4 + r) * 512 + lane * 8;

  f32x4 acc[4][4];
#pragma unroll
  for (int i = 0; i < 4; ++i)
#pragma unroll
    for (int r = 0; r < 4; ++r) acc[i][r] = (f32x4){0.f, 0.f, 0.f, 0.f};

  auto stage = [&](int buf, int kc32) {
#pragma unroll
    for (int c = 0; c < 2; ++c) {
      const u32* gsrc = Aq + (size_t)sRowG[c] * 128 + kc32 * 32 + sOff[c];
      u32* ldst = &As[buf][c * 1024 + wave * 256];
      __builtin_amdgcn_global_load_lds(GLB_PTR(gsrc), LDS_PTR(ldst), 16, 0, 0);
    }
  };

  stage(0, 0);
  __syncthreads();
  int buf = 0;
#pragma unroll
  for (int kc = 0; kc < NK1; ++kc) {
    if (kc + 1 < NK1) stage(buf ^ 1, kc + 1);
    uint4 BH[4], BL[4];
#pragma unroll
    for (int r = 0; r < 4; ++r) {
      BH[r] = *(const uint4*)(W1h + bBase[r] + kc * 8192);
      BL[r] = *(const uint4*)(W1l + bBase[r] + kc * 8192);
    }
    bf16x8 ah[4], al[4];
#pragma unroll
    for (int i = 0; i < 4; ++i) afrag32(As[buf], i * 16 + r16, q, ah[i], al[i]);
#pragma unroll
    for (int r = 0; r < 4; ++r) {
      bf16x8 bh = as_bf16x8(BH[r]);
      bf16x8 bl = as_bf16x8(BL[r]);
#pragma unroll
      for (int i = 0; i < 4; ++i) {
        acc[i][r] = __builtin_amdgcn_mfma_f32_16x16x32_bf16(ah[i], bh, acc[i][r], 0, 0, 0);
        acc[i][r] = __builtin_amdgcn_mfma_f32_16x16x32_bf16(al[i], bh, acc[i][r], 0, 0, 0);
        acc[i][r] = __builtin_amdgcn_mfma_f32_16x16x32_bf16(ah[i], bl, acc[i][r], 0, 0, 0);
      }
    }
    __syncthreads();
    buf ^= 1;
  }

  // epilogue 1 -> fp16 swizzled LDS tile T
#pragma unroll
  for (int r = 0; r < 4; ++r) {
    int col = wave * 64 + r * 16 + r16;
    float bv = bias1[col];
#pragma unroll
    for (int i = 0; i < 4; ++i) {
#pragma unroll
      for (int g = 0; g < 4; ++g) {
        int row = i * 16 + q * 4 + g;
        float v = acc[i][r][g] + bv;
        *(u16*)((char*)T + row * 512 + ((col * 2) ^ ((row & 7) << 4))) = f2h(v);
      }
    }
  }

  // phase 2: T @ W2 (fp16)
#pragma unroll
  for (int i = 0; i < 4; ++i)
#pragma unroll
    for (int r = 0; r < 4; ++r) acc[i][r] = (f32x4){0.f, 0.f, 0.f, 0.f};
  __syncthreads();

#pragma unroll
  for (int kc = 0; kc < 8; ++kc) {
    uint4 BF[4];
#pragma unroll
    for (int r = 0; r < 4; ++r) BF[r] = *(const uint4*)(W2f + bBase[r] + kc * 8192);
    f16x8 af[4];
#pragma unroll
    for (int i = 0; i < 4; ++i) {
      int row = i * 16 + r16;
      int base = kc * 64 + q * 16;
      af[i] = as_f16x8(*(const uint4*)((char*)T + row * 512 + (base ^ ((row & 7) << 4))));
    }
#pragma unroll
    for (int r = 0; r < 4; ++r) {
      f16x8 bf = as_f16x8(BF[r]);
#pragma unroll
      for (int i = 0; i < 4; ++i)
        acc[i][r] = __builtin_amdgcn_mfma_f32_16x16x32_f16(af[i], bf, acc[i][r], 0, 0, 0);
    }
  }

#pragma unroll
  for (int r = 0; r < 4; ++r) {
    int col = wave * 64 + r * 16 + r16;
#pragma unroll
    for (int i = 0; i < 4; ++i) {
#pragma unroll
      for (int g = 0; g < 4; ++g) {
        int row = row0 + i * 16 + q * 4 + g;
        if (row < nrows) C[(size_t)row * 256 + col] = f2h(acc[i][r][g]);
      }
    }
  }
}

// tr(+conv) fused, full fp16, BK=64: A = h_agg fp16; T = relu(A@W1f+bias1) in LDS;
// C = T @ W2f.
__global__ __launch_bounds__(256) void fused_h_kernel(
    const u16* __restrict__ Ah, const u16* __restrict__ W1f, const float* __restrict__ bias1,
    const u16* __restrict__ W2f, u16* __restrict__ C, int nrows) {
  __shared__ __align__(16) u32 As[2][2048];  // 2 x 8KB fp16 A stages (64 rows x 64 fp16)
  __shared__ __align__(16) u16 T[64 * 256];  // 32KB fp16 intermediate
  const int tid = threadIdx.x;
  const int lane = tid & 63;
  const int wave = tid >> 6;
  const int row0 = blockIdx.x * 64;
  const int q = lane >> 4;
  const int r16 = lane & 15;

  int sRowG[2], sOffH[2];
#pragma unroll
  for (int c = 0; c < 2; ++c) {
    int row_l = c * 32 + wave * 8 + (lane >> 3);
    int grow = row0 + row_l;
    if (grow > nrows - 1) grow = nrows - 1;
    sRowG[c] = grow;
    sOffH[c] = ((lane & 7) ^ (row_l & 7)) * 8;  // fp16 units within 64-wide row
  }

  int bBase[4];
#pragma unroll
  for (int r = 0; r < 4; ++r) bBase[r] = (wave * 4 + r) * 512 + lane * 8;

  f32x4 acc[4][4];
#pragma unroll
  for (int i = 0; i < 4; ++i)
#pragma unroll
    for (int r = 0; r < 4; ++r) acc[i][r] = (f32x4){0.f, 0.f, 0.f, 0.f};

  auto stage = [&](int buf, int kc64) {
#pragma unroll
    for (int c = 0; c < 2; ++c) {
      const u16* gsrc = Ah + (size_t)sRowG[c] * 256 + kc64 * 64 + sOffH[c];
      u32* ldst = &As[buf][c * 1024 + wave * 256];
      __builtin_amdgcn_global_load_lds(GLB_PTR(gsrc), LDS_PTR(ldst), 16, 0, 0);
    }
  };

  // ---------- phase 1: A @ W1f (fp16), 4 barriers ----------
  stage(0, 0);
  __syncthreads();
  int buf = 0;
#pragma unroll
  for (int kc = 0; kc < 4; ++kc) {
    if (kc + 1 < 4) stage(buf ^ 1, kc + 1);
#pragma unroll
    for (int ch = 0; ch < 2; ++ch) {
      int kc32 = kc * 2 + ch;
      uint4 BF[4];
#pragma unroll
      for (int r = 0; r < 4; ++r) BF[r] = *(const uint4*)(W1f + bBase[r] + kc32 * 8192);
      f16x8 af[4];
#pragma unroll
      for (int i = 0; i < 4; ++i) af[i] = afrag64(As[buf], i * 16 + r16, ch, q);
#pragma unroll
      for (int r = 0; r < 4; ++r) {
        f16x8 bf = as_f16x8(BF[r]);
#pragma unroll
        for (int i = 0; i < 4; ++i)
          acc[i][r] = __builtin_amdgcn_mfma_f32_16x16x32_f16(af[i], bf, acc[i][r], 0, 0, 0);
      }
    }
    __syncthreads();
    buf ^= 1;
  }

  // epilogue 1 -> fp16 swizzled LDS tile T (relu)
#pragma unroll
  for (int r = 0; r < 4; ++r) {
    int col = wave * 64 + r * 16 + r16;
    float bv = bias1[col];
#pragma unroll
    for (int i = 0; i < 4; ++i) {
#pragma unroll
      for (int g = 0; g < 4; ++g) {
        int row = i * 16 + q * 4 + g;
        float v = fmaxf(acc[i][r][g] + bv, 0.f);
        *(u16*)((char*)T + row * 512 + ((col * 2) ^ ((row & 7) << 4))) = f2h(v);
      }
    }
  }

  // ---------- phase 2: T @ W2f (fp16, barrier-free) ----------
#pragma unroll
  for (int i = 0; i < 4; ++i)
#pragma unroll
    for (int r = 0; r < 4; ++r) acc[i][r] = (f32x4){0.f, 0.f, 0.f, 0.f};
  __syncthreads();

#pragma unroll
  for (int kc = 0; kc < 8; ++kc) {
    uint4 BF[4];
#pragma unroll
    for (int r = 0; r < 4; ++r) BF[r] = *(const uint4*)(W2f + bBase[r] + kc * 8192);
    f16x8 af[4];
#pragma unroll
    for (int i = 0; i < 4; ++i) {
      int row = i * 16 + r16;
      int base = kc * 64 + q * 16;
      af[i] = as_f16x8(*(const uint4*)((char*)T + row * 512 + (base ^ ((row & 7) << 4))));
    }
#pragma unroll
    for (int r = 0; r < 4; ++r) {
      f16x8 bf = as_f16x8(BF[r]);
#pragma unroll
      for (int i = 0; i < 4; ++i)
        acc[i][r] = __builtin_amdgcn_mfma_f32_16x16x32_f16(af[i], bf, acc[i][r], 0, 0, 0);
    }
  }

#pragma unroll
  for (int r = 0; r < 4; ++r) {
    int col = wave * 64 + r * 16 + r16;
#pragma unroll
    for (int i = 0; i < 4; ++i) {
#pragma unroll
      for (int g = 0; g < 4; ++g) {
        int row = row0 + i * 16 + q * 4 + g;
        if (row < nrows) C[(size_t)row * 256 + col] = f2h(acc[i][r][g]);
      }
    }
  }
}

// final tr standalone, fp16, BK=64: C = relu(A @ W1f + bias)
__global__ __launch_bounds__(256) void gemm_h_kernel(
    const u16* __restrict__ Ah, const u16* __restrict__ W1f, const float* __restrict__ bias,
    u16* __restrict__ C, int nrows) {
  __shared__ __align__(16) u32 As[2][2048];
  const int tid = threadIdx.x;
  const int lane = tid & 63;
  const int wave = tid >> 6;
  const int row0 = blockIdx.x * 64;
  const int q = lane >> 4;
  const int r16 = lane & 15;

  int sRowG[2], sOffH[2];
#pragma unroll
  for (int c = 0; c < 2; ++c) {
    int row_l = c * 32 + wave * 8 + (lane >> 3);
    int grow = row0 + row_l;
    if (grow > nrows - 1) grow = nrows - 1;
    sRowG[c] = grow;
    sOffH[c] = ((lane & 7) ^ (row_l & 7)) * 8;
  }

  int bBase[4];
#pragma unroll
  for (int r = 0; r < 4; ++r) bBase[r] = (wave * 4 + r) * 512 + lane * 8;

  f32x4 acc[4][4];
#pragma unroll
  for (int i = 0; i < 4; ++i)
#pragma unroll
    for (int r = 0; r < 4; ++r) acc[i][r] = (f32x4){0.f, 0.f, 0.f, 0.f};

  auto stage = [&](int buf, int kc64) {
#pragma unroll
    for (int c = 0; c < 2; ++c) {
      const u16* gsrc = Ah + (size_t)sRowG[c] * 256 + kc64 * 64 + sOffH[c];
      u32* ldst = &As[buf][c * 1024 + wave * 256];
      __builtin_amdgcn_global_load_lds(GLB_PTR(gsrc), LDS_PTR(ldst), 16, 0, 0);
    }
  };

  stage(0, 0);
  __syncthreads();
  int buf = 0;
#pragma unroll
  for (int kc = 0; kc < 4; ++kc) {
    if (kc + 1 < 4) stage(buf ^ 1, kc + 1);
#pragma unroll
    for (int ch = 0; ch < 2; ++ch) {
      int kc32 = kc * 2 + ch;
      uint4 BF[4];
#pragma unroll
      for (int r = 0; r < 4; ++r) BF[r] = *(const uint4*)(W1f + bBase[r] + kc32 * 8192);
      f16x8 af[4];
#pragma unroll
      for (int i = 0; i < 4; ++i) af[i] = afrag64(As[buf], i * 16 + r16, ch, q);
#pragma unroll
      for (int r = 0; r < 4; ++r) {
        f16x8 bf = as_f16x8(BF[r]);
#pragma unroll
        for (int i = 0; i < 4; ++i)
          acc[i][r] = __builtin_amdgcn_mfma_f32_16x16x32_f16(af[i], bf, acc[i][r], 0, 0, 0);
      }
    }
    __syncthreads();
    buf ^= 1;
  }

#pragma unroll
  for (int r = 0; r < 4; ++r) {
    int col = wave * 64 + r * 16 + r16;
    float bv = bias[col];
#pragma unroll
    for (int i = 0; i < 4; ++i) {
#pragma unroll
      for (int g = 0; g < 4; ++g) {
        int row = row0 + i * 16 + q * 4 + g;
        if (row < nrows) C[(size_t)row * 256 + col] = f2h(fmaxf(acc[i][r][g] + bv, 0.f));
      }
    }
  }
}

// ---------------- GCN gather + fused BN stats, 8-edge unroll ----------------
// m fp16 in, h_agg fp16 out; per-edge (src,norm) precomputed. BN stats fp32.

__global__ __launch_bounds__(256) void gather_kernel(
    const u16* __restrict__ m, const int* __restrict__ off,
    const int2* __restrict__ csrE, const float* __restrict__ dis,
    const float* __restrict__ bias, u16* __restrict__ out,
    float* __restrict__ shard, int n) {
  __shared__ float2 red[4][256];
  int wv = threadIdx.x >> 6;
  int lane = threadIdx.x & 63;
  int node = blockIdx.x * 4 + wv;
  float ax = 0.f, ay = 0.f, az = 0.f, aw = 0.f;
  if (node < n) {
    float di = dis[node];
    uint2 v = *(const uint2*)(m + (size_t)node * DD + lane * 4);
    float w = di * di;
    ax = w * h2f((u16)(v.x & 0xffff)); ay = w * h2f((u16)(v.x >> 16));
    az = w * h2f((u16)(v.y & 0xffff)); aw = w * h2f((u16)(v.y >> 16));
    int e = off[node], e1 = off[node + 1];
    for (; e + 7 < e1; e += 8) {
      int2 p[8];
#pragma unroll
      for (int j = 0; j < 8; ++j) p[j] = csrE[e + j];
      uint2 u[8];
#pragma unroll
      for (int j = 0; j < 8; ++j) u[j] = *(const uint2*)(m + (size_t)p[j].x * DD + lane * 4);
#pragma unroll
      for (int j = 0; j < 8; ++j) {
        float ww = __int_as_float(p[j].y);
        ax = fmaf(ww, h2f((u16)(u[j].x & 0xffff)), ax);
        ay = fmaf(ww, h2f((u16)(u[j].x >> 16)), ay);
        az = fmaf(ww, h2f((u16)(u[j].y & 0xffff)), az);
        aw = fmaf(ww, h2f((u16)(u[j].y >> 16)), aw);
      }
    }
    for (; e + 3 < e1; e += 4) {
      int2 p[4];
#pragma unroll
      for (int j = 0; j < 4; ++j) p[j] = csrE[e + j];
      uint2 u[4];
#pragma unroll
      for (int j = 0; j < 4; ++j) u[j] = *(const uint2*)(m + (size_t)p[j].x * DD + lane * 4);
#pragma unroll
      for (int j = 0; j < 4; ++j) {
        float ww = __int_as_float(p[j].y);
        ax = fmaf(ww, h2f((u16)(u[j].x & 0xffff)), ax);
        ay = fmaf(ww, h2f((u16)(u[j].x >> 16)), ay);
        az = fmaf(ww, h2f((u16)(u[j].y & 0xffff)), az);
        aw = fmaf(ww, h2f((u16)(u[j].y >> 16)), aw);
      }
    }
    for (; e < e1; ++e) {
      int2 p0 = csrE[e];
      float w0 = __int_as_float(p0.y);
      uint2 u0 = *(const uint2*)(m + (size_t)p0.x * DD + lane * 4);
      ax = fmaf(w0, h2f((u16)(u0.x & 0xffff)), ax); ay = fmaf(w0, h2f((u16)(u0.x >> 16)), ay);
      az = fmaf(w0, h2f((u16)(u0.y & 0xffff)), az); aw = fmaf(w0, h2f((u16)(u0.y >> 16)), aw);
    }
    float4 bb = *(const float4*)(bias + lane * 4);
    ax = fmaxf(ax + bb.x, 0.f);
    ay = fmaxf(ay + bb.y, 0.f);
    az = fmaxf(az + bb.z, 0.f);
    aw = fmaxf(aw + bb.w, 0.f);
    uint2 oo;
    oo.x = (u32)f2h(ax) | ((u32)f2h(ay) << 16);
    oo.y = (u32)f2h(az) | ((u32)f2h(aw) << 16);
    *(uint2*)(out + (size_t)node * DD + lane * 4) = oo;
  }
  red[wv][lane * 4 + 0] = make_float2(ax, ax * ax);
  red[wv][lane * 4 + 1] = make_float2(ay, ay * ay);
  red[wv][lane * 4 + 2] = make_float2(az, az * az);
  red[wv][lane * 4 + 3] = make_float2(aw, aw * aw);
  __syncthreads();
  int c = threadIdx.x;
  float2 a = red[0][c], b2 = red[1][c], c2 = red[2][c], d2 = red[3][c];
  float s = (a.x + b2.x) + (c2.x + d2.x);
  float qq = (a.y + b2.y) + (c2.y + d2.y);
  float* sh = shard + (size_t)(blockIdx.x & 63) * 512;
  atomicAdd(&sh[c], s);
  atomicAdd(&sh[256 + c], qq);
}

// ---------------- global mean pool (fp16 h) ----------------

__global__ void pool_kernel(const u16* __restrict__ h, const int* __restrict__ batch,
                            float* __restrict__ pooled, int n) {
  int g = blockIdx.x;
  int c = threadIdx.x;
  int lo = 0, hi = n;
  while (lo < hi) { int mid = (lo + hi) >> 1; if (batch[mid] < g) lo = mid + 1; else hi = mid; }
  int start = lo;
  hi = n;
  while (lo < hi) { int mid = (lo + hi) >> 1; if (batch[mid] <= g) lo = mid + 1; else hi = mid; }
  int end = lo;
  float a0 = 0.f, a1 = 0.f, a2 = 0.f, a3 = 0.f;
  int r = start;
  for (; r + 3 < end; r += 4) {
    a0 += h2f(h[(size_t)(r + 0) * DD + c]);
    a1 += h2f(h[(size_t)(r + 1) * DD + c]);
    a2 += h2f(h[(size_t)(r + 2) * DD + c]);
    a3 += h2f(h[(size_t)(r + 3) * DD + c]);
  }
  for (; r < end; ++r) a0 += h2f(h[(size_t)r * DD + c]);
  float s = (a0 + a1) + (a2 + a3);
  int cg = end - start;
  pooled[g * DD + c] = s / (float)(cg > 1 ? cg : 1);
}

// ---------------- MLP head ----------------

__global__ void mlp1_kernel(const float* __restrict__ pooled, const float* __restrict__ W,
                            const float* __restrict__ b, float* __restrict__ out) {
  __shared__ float p[256];
  int g = blockIdx.x;
  int j = blockIdx.y * 256 + threadIdx.x;
  p[threadIdx.x] = pooled[g * 256 + threadIdx.x];
  __syncthreads();
  float acc = b[j];
#pragma unroll 8
  for (int k = 0; k < 512; ++k) acc = fmaf(p[k & 255], W[k * 512 + j], acc);
  out[g * 512 + j] = fmaxf(acc, 0.f);
}

__global__ void mlp2_kernel(const float* __restrict__ z1, const float* __restrict__ W,
                            const float* __restrict__ b, float* __restrict__ out) {
  __shared__ float p[512];
  int g = blockIdx.x;
  p[threadIdx.x] = z1[g * 512 + threadIdx.x];
  p[256 + threadIdx.x] = z1[g * 512 + 256 + threadIdx.x];
  __syncthreads();
  float acc = b[threadIdx.x];
#pragma unroll 8
  for (int k = 0; k < 512; ++k) acc = fmaf(p[k], W[k * 256 + threadIdx.x], acc);
  out[g * 256 + threadIdx.x] = fmaxf(acc, 0.f);
}

__global__ void mlp3_kernel(const float* __restrict__ z2, const float* __restrict__ W,
                            const float* __restrict__ b, float* __restrict__ out) {
  int g = blockIdx.x;
  int lane = threadIdx.x;
  float acc[10];
#pragma unroll
  for (int o = 0; o < 10; ++o) acc[o] = 0.f;
  for (int k = lane; k < 256; k += 64) {
    float v = z2[g * 256 + k];
#pragma unroll
    for (int o = 0; o < 10; ++o) acc[o] = fmaf(v, W[k * 10 + o], acc[o]);
  }
#pragma unroll
  for (int o = 0; o < 10; ++o) {
    float s = acc[o];
    for (int d = 32; d > 0; d >>= 1) s += __shfl_down(s, d);
    if (lane == 0) out[g * 10 + o] = s + b[o];
  }
}

// ---------------- launch ----------------

extern "C" void kernel_launch(void* const* d_in, const int* in_sizes, int n_in,
                              void* d_out, int out_size, void* d_ws, size_t ws_size,
                              hipStream_t stream) {
  const float* x = (const float*)d_in[0];
  const int* ei = (const int*)d_in[1];
  const int* batch = (const int*)d_in[2];
  const float* fl_W = (const float*)d_in[3];
  const float* fl_b = (const float*)d_in[4];
  const float* conv1_W = (const float*)d_in[5];
  const float* conv1_b = (const float*)d_in[6];
  const float* tr1_W = (const float*)d_in[7];
  const float* tr1_b = (const float*)d_in[8];
  const float* bn1_g = (const float*)d_in[9];
  const float* bn1_b = (const float*)d_in[10];
  const float* convs_W = (const float*)d_in[11];
  const float* convs_b = (const float*)d_in[12];
  const float* trs_W = (const float*)d_in[13];
  const float* trs_b = (const float*)d_in[14];
  const float* bns_g = (const float*)d_in[15];
  const float* bns_b = (const float*)d_in[16];
  const float* l1_W = (const float*)d_in[17];
  const float* l1_b = (const float*)d_in[18];
  const float* l2_W = (const float*)d_in[19];
  const float* l2_b = (const float*)d_in[20];
  const float* l3_W = (const float*)d_in[21];
  const float* l3_b = (const float*)d_in[22];

  const int N = in_sizes[0] / 128;
  const int E = in_sizes[1] / 2;
  const int G = out_size / 10;
  const int NL = in_sizes[11] / (256 * 256);
  const int* src = ei;
  const int* dst = ei + E;

  char* ws = (char*)d_ws;
  size_t o = 0;
  auto alloc = [&](size_t bytes) -> char* {
    o = (o + 255) & ~(size_t)255;
    char* p = ws + o;
    o += bytes;
    return p;
  };
  u16* hA = (u16*)alloc((size_t)N * DD * 2);   // gather out (fp16)
  u16* mF = (u16*)alloc((size_t)N * DD * 2);   // conv out / final h (fp16)
  u32* xq = (u32*)alloc((size_t)N * 128 * 4);  // x bfx2
  float* dis = (float*)alloc((size_t)N * 4);
  int* cnt = (int*)alloc((size_t)N * 4);
  int* off = (int*)alloc((size_t)(N + 1) * 4);
  int* cursor = (int*)alloc((size_t)N * 4);
  int* bsum = (int*)alloc(64 * 4);
  int2* csrE = (int2*)alloc((size_t)E * 8);
  float* shards = (float*)alloc((size_t)(1 + NL) * 64 * 512 * 4);
  float* scalev = (float*)alloc(256 * 4);
  float* shiftv = (float*)alloc(256 * 4);
  float* pooled = (float*)alloc((size_t)G * 256 * 4);
  float* z1 = (float*)alloc((size_t)G * 512 * 4);
  float* z2 = (float*)alloc((size_t)G * 256 * 4);
  u16* flHi = (u16*)alloc(128 * 256 * 2);
  u16* flLo = (u16*)alloc(128 * 256 * 2);
  u16* cvF = (u16*)alloc((size_t)(1 + NL) * 256 * 256 * 2);
  u16* trF = (u16*)alloc(256 * 256 * 2);
  float* trBias = (float*)alloc(256 * 4);

  dim3 b256(256);
  const int nblk = (N + 63) / 64;

  // CSR build
  zero_i32_kernel<<<(N + 255) / 256, b256, 0, stream>>>(cnt, N);
  count_kernel<<<(E + 255) / 256, b256, 0, stream>>>(dst, cnt, E);
  int nb = (N + 1023) / 1024;
  scan_block_kernel<<<nb, b256, 0, stream>>>(cnt, off, bsum, N);
  scan_partials_kernel<<<1, 64, 0, stream>>>(bsum, nb);
  finalize_kernel<<<(N + 255) / 256, b256, 0, stream>>>(off, bsum, cursor, cnt, dis, N, E);
  fill_kernel<<<(E + 255) / 256, b256, 0, stream>>>(src, dst, cursor, dis, csrE, E);

  // prep
  xsplit_kernel<<<(N * 128 + 255) / 256, b256, 0, stream>>>(x, xq, N * 128);
  dim3 wgrid(256, 2 + NL);
  wsplit_all_kernel<<<wgrid, b256, 0, stream>>>(fl_W, conv1_W, convs_W, flHi, flLo, cvF);
  int shard_elems = (1 + NL) * 64 * 512;
  zero_f32_kernel<<<(shard_elems + 255) / 256, b256, 0, stream>>>(shards, shard_elems);

  // fused fl + conv1 -> m1 (fp16)
  fused_fl_kernel<<<nblk, b256, 0, stream>>>(xq, flHi, flLo, fl_b, cvF, mF, N);

  for (int L = 0; L < 1 + NL; ++L) {
    const float* bc = (L == 0) ? conv1_b : convs_b + (size_t)(L - 1) * 256;
    const float* gg = (L == 0) ? bn1_g : bns_g + (size_t)(L - 1) * 256;
    const float* gb = (L == 0) ? bn1_b : bns_b + (size_t)(L - 1) * 256;
    const float* Wt = (L == 0) ? tr1_W : trs_W + (size_t)(L - 1) * 256 * 256;
    const float* bt = (L == 0) ? tr1_b : trs_b + (size_t)(L - 1) * 256;
    float* slot = shards + (size_t)L * 64 * 512;

    gather_kernel<<<(N + 3) / 4, b256, 0, stream>>>(mF, off, csrE, dis, bc, hA, slot, N);
    bn_finalize_kernel<<<1, b256, 0, stream>>>(slot, gg, gb, scalev, shiftv, 1.0f / (float)N);
    wsplit_fold_kernel<<<256, b256, 0, stream>>>(Wt, scalev, shiftv, bt, trF, trBias);
    if (L < NL) {
      fused_h_kernel<<<nblk, b256, 0, stream>>>(hA, trF, trBias,
                                                cvF + (size_t)(L + 1) * 65536, mF, N);
    } else {
      gemm_h_kernel<<<nblk, b256, 0, stream>>>(hA, trF, trBias, mF, N);
    }
  }

  pool_kernel<<<G, b256, 0, stream>>>(mF, batch, pooled, N);
  dim3 m1grid(G, 2);
  mlp1_kernel<<<m1grid, b256, 0, stream>>>(pooled, l1_W, l1_b, z1);
  mlp2_kernel<<<G, b256, 0, stream>>>(z1, l2_W, l2_b, z2);
  mlp3_kernel<<<G, 64, 0, stream>>>(z2, l3_W, l3_b, (float*)d_out);
}